// Round 14
// baseline (742.495 us; speedup 1.0000x reference)
//
#include <hip/hip_runtime.h>
#include <math.h>

#define NN 16500
#define NP 16512      // 129 * 128 padded rows
#define NE 100000
#define KT 3

typedef __attribute__((ext_vector_type(8))) short bf8_t;   // 8 x bf16
typedef __attribute__((ext_vector_type(4))) float f4_t;    // MFMA accumulator

__device__ __forceinline__ unsigned short f2bf(float f) {
    unsigned int u = __float_as_uint(f);
    u += 0x7fffu + ((u >> 16) & 1u);   // RNE
    return (unsigned short)(u >> 16);
}
__device__ __forceinline__ float bf2f(unsigned short h) {
    return __uint_as_float(((unsigned int)h) << 16);
}
__device__ __forceinline__ void gload16(unsigned short* lds, const unsigned short* g) {
    __builtin_amdgcn_global_load_lds(
        (const __attribute__((address_space(1))) void*)g,
        (__attribute__((address_space(3))) void*)lds, 16, 0, 0);
}

// ---------------- CSR build ----------------

__global__ void deg_kernel(const int* __restrict__ ei, int* __restrict__ deg) {
    int t = blockIdx.x * blockDim.x + threadIdx.x;
    if (t >= KT * NE) return;
    int k = t / NE, e = t - k * NE;
    int d = ei[k * 2 * NE + NE + e];
    atomicAdd(&deg[k * NN + d], 1);
}

__global__ void scan_kernel(const int* __restrict__ deg, int* __restrict__ offs,
                            int* __restrict__ cursor) {
    int k = blockIdx.x;
    const int* dg = deg + k * NN;
    int* of = offs + k * (NN + 1);
    int* cu = cursor + k * NN;
    __shared__ int part[256];
    int tid = threadIdx.x;
    const int chunk = (NN + 255) / 256;
    int s0 = tid * chunk, s1 = min(NN, s0 + chunk);
    if (s0 > s1) s0 = s1;
    int sum = 0;
    for (int i = s0; i < s1; ++i) sum += dg[i];
    part[tid] = sum;
    __syncthreads();
    for (int off = 1; off < 256; off <<= 1) {
        int v = part[tid];
        int vp = (tid >= off) ? part[tid - off] : 0;
        __syncthreads();
        part[tid] = v + vp;
        __syncthreads();
    }
    int run = (tid == 0) ? 0 : part[tid - 1];
    for (int i = s0; i < s1; ++i) {
        of[i] = run; cu[i] = run;
        run += dg[i];
    }
    if (tid == 255) of[NN] = run;
}

// scatter edge (src, ea) pairs directly in CSR order — removes one dependent
// gather level from the aggregation critical path.
__global__ void scatter_kernel(const int* __restrict__ ei, const float* __restrict__ ea,
                               int* __restrict__ cursor, int2* __restrict__ se) {
    int t = blockIdx.x * blockDim.x + threadIdx.x;
    if (t >= KT * NE) return;
    int k = t / NE, e = t - k * NE;
    int s = ei[k * 2 * NE + e];
    int d = ei[k * 2 * NE + NE + e];
    float a = ea[(size_t)k * NE + e];
    int pos = atomicAdd(&cursor[k * NN + d], 1);
    int2 p; p.x = s; p.y = __float_as_int(a);
    se[(size_t)k * NE + pos] = p;
}

// ---------------- softmax aggregation: one wave per (dst,k), 4 dsts/wave, depth-4 pipeline ----
// No-max online softmax: msg = relu(x_src + a*We + be) is bounded well below the
// fp32 exp overflow point for this BN-normalized pipeline, so we accumulate
// den = sum exp(msg), num = sum msg*exp(msg) directly.

template<int CI, bool BF16X>
__device__ __forceinline__ void loadrow4(float out[4], const void* xv, int s, int c0) {
    if (BF16X) {
        const unsigned short* xb = (const unsigned short*)xv;
        uint2 u = *(const uint2*)(xb + (size_t)s * CI + c0);
        out[0] = bf2f((unsigned short)(u.x & 0xffffu));
        out[1] = bf2f((unsigned short)(u.x >> 16));
        out[2] = bf2f((unsigned short)(u.y & 0xffffu));
        out[3] = bf2f((unsigned short)(u.y >> 16));
    } else {
        const float* p = (const float*)xv + (size_t)s * CI + c0;
        if (c0 + 4 <= CI) {
            float2 ab = *(const float2*)p;
            float2 cd = *(const float2*)(p + 2);
            out[0] = ab.x; out[1] = ab.y; out[2] = cd.x; out[3] = cd.y;
        } else {
            #pragma unroll
            for (int e = 0; e < 4; ++e) out[e] = (c0 + e < CI) ? p[e] : 0.f;
        }
    }
}

template<int CI, bool BF16X>
__global__ __launch_bounds__(256) void aggr_kernel(
    const void* __restrict__ xv, const int2* __restrict__ se_all,
    const int* __restrict__ offs_all,
    const float* __restrict__ We_all, const float* __restrict__ be_all,
    unsigned short* __restrict__ out_hi)
{
    constexpr int KP = (CI + 31) / 32 * 32;
    int k = blockIdx.y;
    int wv = threadIdx.x >> 6, lane = threadIdx.x & 63;
    int c0 = lane * 4;
    unsigned short* o = out_hi + (size_t)k * NP * KP;
    const int2*  se   = se_all + (size_t)k * NE;
    const int*   offs = offs_all + k * (NN + 1);
    const float* We   = We_all + (size_t)k * CI;
    const float* be   = be_all + (size_t)k * CI;

    constexpr bool ACT_ALL = (64 * 4 == KP) && (CI == KP);
    bool act = ACT_ALL || (c0 < CI);
    float w[4], b[4];
    #pragma unroll
    for (int e = 0; e < 4; ++e) {
        bool a = (c0 + e) < CI;
        w[e] = a ? We[c0 + e] : 0.f;
        b[e] = a ? be[c0 + e] : 0.f;
    }

    for (int it = 0; it < 4; ++it) {
        int d = blockIdx.x * 16 + it * 4 + wv;
        if (d >= NN) {
            if (c0 < KP) { uint2 z = {0u, 0u}; *(uint2*)(o + (size_t)d * KP + c0) = z; }
            continue;
        }
        float xd[4] = {0.f, 0.f, 0.f, 0.f};
        if (act) loadrow4<CI, BF16X>(xd, xv, d, c0);
        #pragma unroll
        for (int e = 0; e < 4; ++e) if ((c0 + e) >= CI) xd[e] = 0.f;

        float den[4], num[4];
        #pragma unroll
        for (int e = 0; e < 4; ++e) {
            float mg = fmaxf(xd[e] + w[e] + b[e], 0.f);   // self loop, ea=1
            float ex = __expf(mg);
            den[e] = ex;
            num[e] = mg * ex;
        }

        auto step = [&](const float xc[4], float a) {
            #pragma unroll
            for (int e = 0; e < 4; ++e) {
                float t = xc[e] + fmaf(a, w[e], b[e]);
                float mg = fmaxf(t, 0.f);
                float ex = __expf(mg);
                den[e] += ex;
                num[e] = fmaf(mg, ex, num[e]);
            }
        };

        int start = offs[d], end = offs[d + 1];
        for (int base = start; base < end; base += 64) {
            int cnt = min(64, end - base);
            int sv = 0; float av = 0.f;
            if (lane < cnt) {
                int2 p = se[base + lane];
                sv = p.x; av = __int_as_float(p.y);
            }
            float x0[4] = {0.f,0.f,0.f,0.f}, x1[4] = {0.f,0.f,0.f,0.f};
            float x2[4] = {0.f,0.f,0.f,0.f}, x3[4] = {0.f,0.f,0.f,0.f};
            {
                int sA = __shfl(sv, 0), sB = __shfl(sv, 1);
                int sC = __shfl(sv, 2), sD = __shfl(sv, 3);
                if (act)            loadrow4<CI, BF16X>(x0, xv, sA, c0);
                if (act && cnt > 1) loadrow4<CI, BF16X>(x1, xv, sB, c0);
                if (act && cnt > 2) loadrow4<CI, BF16X>(x2, xv, sC, c0);
                if (act && cnt > 3) loadrow4<CI, BF16X>(x3, xv, sD, c0);
            }
            int j = 0;
            for (; j + 3 < cnt; j += 4) {
                float a0 = __shfl(av, j),     a1 = __shfl(av, j + 1);
                float a2 = __shfl(av, j + 2), a3 = __shfl(av, j + 3);
                int s4 = __shfl(sv, (j + 4) & 63), s5 = __shfl(sv, (j + 5) & 63);
                int s6 = __shfl(sv, (j + 6) & 63), s7 = __shfl(sv, (j + 7) & 63);
                step(x0, a0);
                if (act && (j + 4) < cnt) loadrow4<CI, BF16X>(x0, xv, s4, c0);
                step(x1, a1);
                if (act && (j + 5) < cnt) loadrow4<CI, BF16X>(x1, xv, s5, c0);
                step(x2, a2);
                if (act && (j + 6) < cnt) loadrow4<CI, BF16X>(x2, xv, s6, c0);
                step(x3, a3);
                if (act && (j + 7) < cnt) loadrow4<CI, BF16X>(x3, xv, s7, c0);
            }
            if (j < cnt)     step(x0, __shfl(av, j));
            if (j + 1 < cnt) step(x1, __shfl(av, j + 1));
            if (j + 2 < cnt) step(x2, __shfl(av, j + 2));
        }
        if (c0 < KP) {
            unsigned short r[4];
            #pragma unroll
            for (int e = 0; e < 4; ++e) {
                float v = ((c0 + e) < CI) ? (num[e] / den[e] + xd[e]) : 0.f;
                r[e] = f2bf(v);
            }
            uint2 pk = {(unsigned)r[0] | ((unsigned)r[1] << 16),
                        (unsigned)r[2] | ((unsigned)r[3] << 16)};
            *(uint2*)(o + (size_t)d * KP + c0) = pk;
        }
    }
}

// ---------------- weight split+transpose, all 6 jobs in one launch ----------------

struct SplitJob { const float* W; unsigned short* out; int kdim, ndim, np_, kp; };
struct SplitJobs { SplitJob j[6]; };

__global__ void split_all_kernel(SplitJobs jobs) {
    SplitJob jb = jobs.j[blockIdx.z];
    int idx = blockIdx.x * 256 + threadIdx.x;
    int total = KT * jb.np_ * jb.kp;
    if (idx >= total) return;
    int k = idx / (jb.np_ * jb.kp);
    int rem = idx - k * jb.np_ * jb.kp;
    int n = rem / jb.kp;
    int kk = rem - n * jb.kp;
    float v = (n < jb.ndim && kk < jb.kdim) ? jb.W[((size_t)k * jb.kdim + kk) * jb.ndim + n] : 0.f;
    jb.out[idx] = f2bf(v);
}

// ---------------- GEMM1: bf16 MFMA, dbuf K-loop, fused BN stats, LDS-coalesced C store ------
// (round-9 win: LDS C-bounce removes ~4.8x HBM write amplification)

__global__ __launch_bounds__(256, 2) void gemm1_mfma(
    const unsigned short* __restrict__ A_hi,
    const unsigned short* __restrict__ B_hi,
    const float* __restrict__ bias_all, unsigned short* __restrict__ C_all,
    float* __restrict__ psum,
    int KP, int ldc, int Mv, int Nv)
{
    __shared__ unsigned short smem[16384];   // A dbuf [0|4096], B dbuf [8192|12288]; reused as Ct[128][128]

    int z = blockIdx.z;
    int gxT = gridDim.x, gyT = gridDim.y;
    int NHP = gxT * 128;
    const unsigned short* Ahg = A_hi + (size_t)z * NP * KP;
    const unsigned short* Bhg = B_hi + (size_t)z * NHP * KP;
    const float* bias = bias_all + (size_t)z * Nv;
    unsigned short* C = C_all + (size_t)z * NP * ldc;

    int tid = threadIdx.x;
    int w = tid >> 6, l = tid & 63;
    int bm = blockIdx.y * 128, bn = blockIdx.x * 128;
    int lane15 = l & 15, quad = l >> 4;
    int wm = (w >> 1) * 64, wn = (w & 1) * 64;
    int srow = l & 15;
    int scol = (l >> 4) * 8;

    f4_t acc[4][4];
    #pragma unroll
    for (int i = 0; i < 4; ++i)
        #pragma unroll
        for (int j = 0; j < 4; ++j) { f4_t zz = {0.f,0.f,0.f,0.f}; acc[i][j] = zz; }

    size_t aoff0 = (size_t)(bm + 32 * w +  0 + srow) * KP + scol;
    size_t aoff1 = (size_t)(bm + 32 * w + 16 + srow) * KP + scol;
    size_t boff0 = (size_t)(bn + 32 * w +  0 + srow) * KP + scol;
    size_t boff1 = (size_t)(bn + 32 * w + 16 + srow) * KP + scol;
    int rb0 = 32 * w, rb1 = 32 * w + 16;
    int ta = (w >> 1) * 4, tb = (w & 1) * 4;

    // prologue: stage tile 0 into offset 0
    gload16(&smem[0 + rb0 * 32], Ahg + aoff0);
    gload16(&smem[0 + rb1 * 32], Ahg + aoff1);
    gload16(&smem[8192 + rb0 * 32], Bhg + boff0);
    gload16(&smem[8192 + rb1 * 32], Bhg + boff1);
    __syncthreads();

    int curo = 0;
    for (int k0 = 32; k0 < KP; k0 += 32) {
        int nxto = curo ^ 4096;
        gload16(&smem[nxto + rb0 * 32], Ahg + aoff0 + k0);
        gload16(&smem[nxto + rb1 * 32], Ahg + aoff1 + k0);
        gload16(&smem[8192 + nxto + rb0 * 32], Bhg + boff0 + k0);
        gload16(&smem[8192 + nxto + rb1 * 32], Bhg + boff1 + k0);

        bf8_t fa[4], fb[4];
        #pragma unroll
        for (int i = 0; i < 4; ++i) {
            fa[i] = *(const bf8_t*)&smem[curo + (ta + i) * 512 + l * 8];
            fb[i] = *(const bf8_t*)&smem[8192 + curo + (tb + i) * 512 + l * 8];
        }
        #pragma unroll
        for (int i = 0; i < 4; ++i)
            #pragma unroll
            for (int j = 0; j < 4; ++j)
                acc[i][j] = __builtin_amdgcn_mfma_f32_16x16x32_bf16(fa[i], fb[j], acc[i][j], 0, 0, 0);
        __syncthreads();
        curo = nxto;
    }
    {   // last tile
        bf8_t fa[4], fb[4];
        #pragma unroll
        for (int i = 0; i < 4; ++i) {
            fa[i] = *(const bf8_t*)&smem[curo + (ta + i) * 512 + l * 8];
            fb[i] = *(const bf8_t*)&smem[8192 + curo + (tb + i) * 512 + l * 8];
        }
        #pragma unroll
        for (int i = 0; i < 4; ++i)
            #pragma unroll
            for (int j = 0; j < 4; ++j)
                acc[i][j] = __builtin_amdgcn_mfma_f32_16x16x32_bf16(fa[i], fb[j], acc[i][j], 0, 0, 0);
    }

    __syncthreads();   // all waves done reading staging buffers; safe to reuse as C tile

    // quantize + fused BN partial stats (identical arithmetic to before); C -> LDS
    #pragma unroll
    for (int j = 0; j < 4; ++j) {
        int c = bn + wn + j * 16 + lane15;
        float bc = (c < Nv) ? bias[c] : 0.f;
        float s1 = 0.f, s2 = 0.f;
        #pragma unroll
        for (int i = 0; i < 4; ++i) {
            #pragma unroll
            for (int r5 = 0; r5 < 4; ++r5) {
                int r = bm + wm + i * 16 + quad * 4 + r5;
                float v = acc[i][j][r5] + bc;
                unsigned short q = f2bf(v);
                int lr = wm + i * 16 + quad * 4 + r5;
                int lc = wn + j * 16 + lane15;
                smem[lr * 128 + lc] = q;
                bool ok = (r < NN) && (c < Nv);
                float vq = ok ? bf2f(q) : 0.f;
                s1 += vq;
                s2 = fmaf(vq, vq, s2);
            }
        }
        s1 += __shfl_xor(s1, 16); s2 += __shfl_xor(s2, 16);
        s1 += __shfl_xor(s1, 32); s2 += __shfl_xor(s2, 32);
        if (quad == 0) {
            int wrow = w >> 1;
            int col = wn + j * 16 + lane15;
            size_t o = ((((size_t)z * gyT + blockIdx.y) * gxT + blockIdx.x) * 2 + wrow) * 256 + col * 2;
            float2 st = {s1, s2};
            *(float2*)&psum[o] = st;
        }
    }
    __syncthreads();

    // coalesced C store: 16 lanes x 16B = 256B contiguous per row segment
    int lr8 = tid >> 4;              // row 0..15 base
    int lc8 = (tid & 15) * 8;        // col 0..120
    bool cok = (bn + lc8 + 8) <= ldc;
    if (cok) {
        #pragma unroll
        for (int p = 0; p < 8; ++p) {
            int row = p * 16 + lr8;
            uint4 v = *(const uint4*)&smem[row * 128 + lc8];
            *(uint4*)&C[(size_t)(bm + row) * ldc + bn + lc8] = v;
        }
    }
}

// ---------------- finalize BN scale/shift from partials (parallel over channel chunks) ---------

__global__ __launch_bounds__(256) void finalize_kernel(
    const float* __restrict__ psum,
    const float* __restrict__ g_all, const float* __restrict__ bt_all,
    float* __restrict__ scale_all, float* __restrict__ shift_all,
    int hid, int gxT)
{
    int z = blockIdx.x;
    int t64 = threadIdx.x & 63;
    int slice = threadIdx.x >> 6;          // 0..3 gy-slices
    int c = blockIdx.y * 64 + t64;         // channel
    __shared__ double rs1[4][64];
    __shared__ double rs2[4][64];
    double s1 = 0.0, s2 = 0.0;
    if (c < gxT * 128) {
        int gx = c >> 7, col = c & 127;
        for (int gy = slice; gy < NP / 128; gy += 4) {
            size_t base = (((size_t)z * (NP / 128) + gy) * gxT + gx) * 2 * 256 + col * 2;
            float2 a  = *(const float2*)&psum[base];
            float2 b2 = *(const float2*)&psum[base + 256];
            s1 += (double)a.x + b2.x;
            s2 += (double)a.y + b2.y;
        }
    }
    rs1[slice][t64] = s1;
    rs2[slice][t64] = s2;
    __syncthreads();
    if (slice == 0 && c < hid) {
        double S1 = rs1[0][t64] + rs1[1][t64] + rs1[2][t64] + rs1[3][t64];
        double S2 = rs2[0][t64] + rs2[1][t64] + rs2[2][t64] + rs2[3][t64];
        double mu = S1 / NN;
        double var = S2 / NN - mu * mu;
        if (var < 0.0) var = 0.0;
        float rs = (float)(1.0 / sqrt(var + 1e-5));
        float sc = rs * g_all[(size_t)z * hid + c];
        scale_all[(size_t)z * 512 + c] = sc;
        shift_all[(size_t)z * 512 + c] = bt_all[(size_t)z * hid + c] - (float)mu * sc;
    }
}

// ---------------- GEMM2: round-10 structure, BK=64 per barrier (half the drains) ------------
// 64x128 tile, all operands via global_load_lds, LDS scale/shift copy, 2-buffer drain
// barrier — identical to the 68.5us round-10 kernel except each iteration covers TWO
// 32-k subtiles: NIT 48->24, compute per drain doubles (16 MFMAs), drain count halves.
// LDS 60KB is free: the 516-block grid caps residency at 2 blocks/CU regardless.
// KP is a multiple of 64 (host pads; split zero-fills B, BN ch<hid guard zeroes A).

__global__ __launch_bounds__(256, 2) void gemm2_mfma(
    const unsigned short* __restrict__ h_all, const float* __restrict__ scale_all,
    const float* __restrict__ shift_all,
    const unsigned short* __restrict__ B_hi,
    const float* __restrict__ bb,
    float* __restrict__ outf, unsigned short* __restrict__ outb,
    int KP, int hid, int leaky, int as_bf16)
{
    __shared__ unsigned short Ah[2][8 * 512];    // 16 KB: [ksub(2)][rowfrag(4)], frag-major
    __shared__ unsigned short Bh[2][16 * 512];   // 32 KB: [ksub(2)][colfrag(8)]
    __shared__ float sclS[KT * 512];             // 6 KB
    __shared__ float shfS[KT * 512];             // 6 KB

    int tid = threadIdx.x;
    int w = tid >> 6, l = tid & 63;
    int bm = blockIdx.y * 64, bn = blockIdx.x * 128;
    int lane15 = l & 15, quad = l >> 4;
    int wm = (w >> 1) * 32, wn = (w & 1) * 64;
    int srow = l & 15, scol = quad * 8;

    const int KPZ = KP / 64;
    const int NIT = 3 * KPZ;

    f4_t acc[2][4];
    #pragma unroll
    for (int i = 0; i < 2; ++i)
        #pragma unroll
        for (int j = 0; j < 4; ++j) { f4_t zz = {0.f,0.f,0.f,0.f}; acc[i][j] = zz; }

    int ta = (w >> 1) * 2, tb = (w & 1) * 4;
    // A: wave w stages rowfrag w (rows bm+16w..+15); lane l -> row lane15, col quad*8
    size_t arow  = (size_t)(bm + 16 * w + lane15) * KP + quad * 8;
    int adst = w * 512 + l * 8;
    // B: wave w stages colfrags 2w, 2w+1 (rows bn+32w..+31)
    size_t brow0 = (size_t)(bn + 32 * w + srow) * KP + scol;
    size_t brow1 = brow0 + (size_t)16 * KP;
    int bdst0 = (2 * w) * 512 + l * 8;
    int bdst1 = (2 * w + 1) * 512 + l * 8;

    auto stage = [&](int t, int s) {
        int zz = t / KPZ, kk = (t - zz * KPZ) * 64;
        const unsigned short* hz = h_all + (size_t)zz * NP * KP + kk;
        const unsigned short* bz = B_hi + (size_t)zz * 256 * KP + kk;
        gload16(&Ah[s][adst], hz + arow);                    // ksub 0
        gload16(&Ah[s][4 * 512 + adst], hz + arow + 32);     // ksub 1
        gload16(&Bh[s][bdst0], bz + brow0);
        gload16(&Bh[s][bdst1], bz + brow1);
        gload16(&Bh[s][8 * 512 + bdst0], bz + brow0 + 32);
        gload16(&Bh[s][8 * 512 + bdst1], bz + brow1 + 32);
    };

    // prologue: scale/shift -> LDS; stage tile 0
    for (int idx = tid; idx < KT * 512; idx += 256) {
        sclS[idx] = scale_all[idx];
        shfS[idx] = shift_all[idx];
    }
    stage(0, 0);
    __syncthreads();

    int cur = 0;
    for (int it = 0; it < NIT; ++it) {
        int nxt = cur ^ 1;
        if (it + 1 < NIT) stage(it + 1, nxt);
        int zz = it / KPZ, kk = (it - zz * KPZ) * 64;
        #pragma unroll
        for (int ks = 0; ks < 2; ++ks) {
            int chb = kk + ks * 32 + quad * 8;
            float4 s0 = *(const float4*)&sclS[zz * 512 + chb];
            float4 s1 = *(const float4*)&sclS[zz * 512 + chb + 4];
            float4 t0 = *(const float4*)&shfS[zz * 512 + chb];
            float4 t1 = *(const float4*)&shfS[zz * 512 + chb + 4];
            float ss[8] = {s0.x, s0.y, s0.z, s0.w, s1.x, s1.y, s1.z, s1.w};
            float tt[8] = {t0.x, t0.y, t0.z, t0.w, t1.x, t1.y, t1.z, t1.w};
            bf8_t fr0 = *(const bf8_t*)&Ah[cur][(ks * 4 + ta + 0) * 512 + l * 8];
            bf8_t fr1 = *(const bf8_t*)&Ah[cur][(ks * 4 + ta + 1) * 512 + l * 8];
            bf8_t fb[4];
            #pragma unroll
            for (int j = 0; j < 4; ++j)
                fb[j] = *(const bf8_t*)&Bh[cur][(ks * 8 + tb + j) * 512 + l * 8];
            bf8_t fa0, fa1;
            #pragma unroll
            for (int e = 0; e < 8; ++e) {
                bool okc = (chb + e) < hid;
                float x0 = bf2f((unsigned short)fr0[e]);
                float x1 = bf2f((unsigned short)fr1[e]);
                float v0 = okc ? fmaxf(fmaf(x0, ss[e], tt[e]), 0.f) : 0.f;
                float v1 = okc ? fmaxf(fmaf(x1, ss[e], tt[e]), 0.f) : 0.f;
                fa0[e] = (short)f2bf(v0);
                fa1[e] = (short)f2bf(v1);
            }
            #pragma unroll
            for (int j = 0; j < 4; ++j) {
                acc[0][j] = __builtin_amdgcn_mfma_f32_16x16x32_bf16(fa0, fb[j], acc[0][j], 0, 0, 0);
                acc[1][j] = __builtin_amdgcn_mfma_f32_16x16x32_bf16(fa1, fb[j], acc[1][j], 0, 0, 0);
            }
        }
        __syncthreads();   // drains the 6 prefetch DMAs + publishes next buffer
        cur = nxt;
    }

    // epilogue: + sum-of-biases, leaky, store final (acc already sums the 3 link types)
    #pragma unroll
    for (int j = 0; j < 4; ++j) {
        int c = bn + wn + j * 16 + lane15;
        float bsum = bb[c] + bb[256 + c] + bb[512 + c];
        #pragma unroll
        for (int i = 0; i < 2; ++i) {
            #pragma unroll
            for (int r5 = 0; r5 < 4; ++r5) {
                int r = bm + wm + i * 16 + quad * 4 + r5;
                if (r < NN) {
                    float v = acc[i][j][r5] + bsum;
                    if (leaky) v = (v > 0.f) ? v : 0.01f * v;
                    if (as_bf16) outb[(size_t)r * 256 + c] = f2bf(v);
                    else         outf[(size_t)r * 256 + c] = v;
                }
            }
        }
    }
}

// ---------------- host ----------------

extern "C" void kernel_launch(void* const* d_in, const int* in_sizes, int n_in,
                              void* d_out, int out_size, void* d_ws, size_t ws_size,
                              hipStream_t stream)
{
    const float* x  = (const float*)d_in[0];
    const int*   ei = (const int*)d_in[1];
    const float* ea = (const float*)d_in[2];

    char* w = (char*)d_ws;
    auto alloc = [&](size_t bytes) {
        char* p = w;
        w += (bytes + 255) & ~(size_t)255;
        return p;
    };
    int* deg    = (int*)alloc((size_t)KT * NN * 4);
    int* offs   = (int*)alloc((size_t)KT * (NN + 1) * 4);
    int* cursor = (int*)alloc((size_t)KT * NN * 4);
    int2* se    = (int2*)alloc((size_t)KT * NE * 8);
    unsigned short* a1_hi = (unsigned short*)alloc((size_t)KT * NP * 256 * 2);
    unsigned short* h3 = (unsigned short*)alloc((size_t)KT * NP * 512 * 2);
    unsigned short* bta_l[3];
    unsigned short* btb_l[3];
    for (int l = 0; l < 3; ++l) {
        bta_l[l] = (unsigned short*)alloc((size_t)KT * 512 * 256 * 2);
        btb_l[l] = (unsigned short*)alloc((size_t)KT * 256 * 512 * 2);
    }
    float* psum = (float*)alloc((size_t)KT * (NP / 128) * 4 * 2 * 256 * 4);
    float* scale3 = (float*)alloc((size_t)KT * 512 * 4);
    float* shift3 = (float*)alloc((size_t)KT * 512 * 4);
    unsigned short* bufA = (unsigned short*)alloc((size_t)NN * 256 * 2);
    unsigned short* bufB = (unsigned short*)alloc((size_t)NN * 256 * 2);

    (void)hipMemsetAsync(deg, 0, (size_t)KT * NN * 4, stream);
    int net = KT * NE;
    deg_kernel<<<(net + 255) / 256, 256, 0, stream>>>(ei, deg);
    scan_kernel<<<KT, 256, 0, stream>>>(deg, offs, cursor);
    scatter_kernel<<<(net + 255) / 256, 256, 0, stream>>>(ei, ea, cursor, se);

    SplitJobs jobs;
    int maxtot = 0;
    for (int l = 0; l < 3; ++l) {
        int ci  = (l == 0) ? 170 : 256;
        int KP1 = (ci + 31) / 32 * 32;
        int hid = 2 * ci;
        int NHP = (hid + 127) / 128 * 128;
        int KP2 = (hid + 63) / 64 * 64;       // 64-padded for gemm2's BK=64
        jobs.j[2 * l]     = { (const float*)d_in[3 + 8 * l + 2], bta_l[l], ci,  hid, NHP, KP1 };
        jobs.j[2 * l + 1] = { (const float*)d_in[3 + 8 * l + 6], btb_l[l], hid, 256, 256, KP2 };
        maxtot = max(maxtot, KT * NHP * KP1);
        maxtot = max(maxtot, KT * 256 * KP2);
    }
    dim3 gsp((maxtot + 255) / 256, 1, 6);
    split_all_kernel<<<gsp, 256, 0, stream>>>(jobs);

    const void* hin = x;
    for (int l = 0; l < 3; ++l) {
        int ci  = (l == 0) ? 170 : 256;
        int KP1 = (ci + 31) / 32 * 32;        // 192 / 256
        int hid = 2 * ci;                     // 340 / 512
        int NHP = (hid + 127) / 128 * 128;    // 384 / 512
        int KP2 = (hid + 63) / 64 * 64;       // 384 / 512 (64-padded for BK=64)
        const float* We = (const float*)d_in[3 + 8 * l + 0];
        const float* be = (const float*)d_in[3 + 8 * l + 1];
        const float* ba = (const float*)d_in[3 + 8 * l + 3];
        const float* g  = (const float*)d_in[3 + 8 * l + 4];
        const float* bt = (const float*)d_in[3 + 8 * l + 5];
        const float* bb = (const float*)d_in[3 + 8 * l + 7];

        dim3 ga(NP / 16, KT);
        if (l == 0)
            aggr_kernel<170, false><<<ga, 256, 0, stream>>>(hin, se, offs, We, be, a1_hi);
        else
            aggr_kernel<256, true><<<ga, 256, 0, stream>>>(hin, se, offs, We, be, a1_hi);

        dim3 g1(NHP / 128, NP / 128, KT);
        gemm1_mfma<<<g1, 256, 0, stream>>>(a1_hi, bta_l[l], ba, h3, psum, KP1, KP2, NN, hid);

        dim3 gf(KT, 8);
        finalize_kernel<<<gf, 256, 0, stream>>>(psum, g, bt, scale3, shift3, hid, NHP / 128);

        unsigned short* outb = (l == 0) ? bufA : bufB;
        dim3 g2(2, NP / 64);
        gemm2_mfma<<<g2, 256, 0, stream>>>(h3, scale3, shift3, btb_l[l], bb,
                                           (float*)d_out, outb, KP2, hid,
                                           (l < 2) ? 1 : 0, (l < 2) ? 1 : 0);

        hin = (l < 2) ? (const void*)outb : nullptr;
    }
}

// Round 15
// 647.965 us; speedup vs baseline: 1.1459x; 1.1459x over previous
//
#include <hip/hip_runtime.h>
#include <math.h>

#define NN 16500
#define NP 16512      // 129 * 128 padded rows
#define NE 100000
#define KT 3

typedef __attribute__((ext_vector_type(8))) short bf8_t;   // 8 x bf16
typedef __attribute__((ext_vector_type(4))) float f4_t;    // MFMA accumulator

__device__ __forceinline__ unsigned short f2bf(float f) {
    unsigned int u = __float_as_uint(f);
    u += 0x7fffu + ((u >> 16) & 1u);   // RNE
    return (unsigned short)(u >> 16);
}
__device__ __forceinline__ float bf2f(unsigned short h) {
    return __uint_as_float(((unsigned int)h) << 16);
}
__device__ __forceinline__ void gload16(unsigned short* lds, const unsigned short* g) {
    __builtin_amdgcn_global_load_lds(
        (const __attribute__((address_space(1))) void*)g,
        (__attribute__((address_space(3))) void*)lds, 16, 0, 0);
}

// ---------------- CSR build ----------------

__global__ void deg_kernel(const int* __restrict__ ei, int* __restrict__ deg) {
    int t = blockIdx.x * blockDim.x + threadIdx.x;
    if (t >= KT * NE) return;
    int k = t / NE, e = t - k * NE;
    int d = ei[k * 2 * NE + NE + e];
    atomicAdd(&deg[k * NN + d], 1);
}

__global__ void scan_kernel(const int* __restrict__ deg, int* __restrict__ offs,
                            int* __restrict__ cursor) {
    int k = blockIdx.x;
    const int* dg = deg + k * NN;
    int* of = offs + k * (NN + 1);
    int* cu = cursor + k * NN;
    __shared__ int part[256];
    int tid = threadIdx.x;
    const int chunk = (NN + 255) / 256;
    int s0 = tid * chunk, s1 = min(NN, s0 + chunk);
    if (s0 > s1) s0 = s1;
    int sum = 0;
    for (int i = s0; i < s1; ++i) sum += dg[i];
    part[tid] = sum;
    __syncthreads();
    for (int off = 1; off < 256; off <<= 1) {
        int v = part[tid];
        int vp = (tid >= off) ? part[tid - off] : 0;
        __syncthreads();
        part[tid] = v + vp;
        __syncthreads();
    }
    int run = (tid == 0) ? 0 : part[tid - 1];
    for (int i = s0; i < s1; ++i) {
        of[i] = run; cu[i] = run;
        run += dg[i];
    }
    if (tid == 255) of[NN] = run;
}

// scatter edge (src, ea) pairs directly in CSR order — removes one dependent
// gather level from the aggregation critical path.
__global__ void scatter_kernel(const int* __restrict__ ei, const float* __restrict__ ea,
                               int* __restrict__ cursor, int2* __restrict__ se) {
    int t = blockIdx.x * blockDim.x + threadIdx.x;
    if (t >= KT * NE) return;
    int k = t / NE, e = t - k * NE;
    int s = ei[k * 2 * NE + e];
    int d = ei[k * 2 * NE + NE + e];
    float a = ea[(size_t)k * NE + e];
    int pos = atomicAdd(&cursor[k * NN + d], 1);
    int2 p; p.x = s; p.y = __float_as_int(a);
    se[(size_t)k * NE + pos] = p;
}

// ---------------- softmax aggregation: one wave per (dst,k), 4 dsts/wave, depth-4 pipeline ----
// No-max online softmax: msg = relu(x_src + a*We + be) is bounded well below the
// fp32 exp overflow point for this BN-normalized pipeline, so we accumulate
// den = sum exp(msg), num = sum msg*exp(msg) directly.

template<int CI, bool BF16X>
__device__ __forceinline__ void loadrow4(float out[4], const void* xv, int s, int c0) {
    if (BF16X) {
        const unsigned short* xb = (const unsigned short*)xv;
        uint2 u = *(const uint2*)(xb + (size_t)s * CI + c0);
        out[0] = bf2f((unsigned short)(u.x & 0xffffu));
        out[1] = bf2f((unsigned short)(u.x >> 16));
        out[2] = bf2f((unsigned short)(u.y & 0xffffu));
        out[3] = bf2f((unsigned short)(u.y >> 16));
    } else {
        const float* p = (const float*)xv + (size_t)s * CI + c0;
        if (c0 + 4 <= CI) {
            float2 ab = *(const float2*)p;
            float2 cd = *(const float2*)(p + 2);
            out[0] = ab.x; out[1] = ab.y; out[2] = cd.x; out[3] = cd.y;
        } else {
            #pragma unroll
            for (int e = 0; e < 4; ++e) out[e] = (c0 + e < CI) ? p[e] : 0.f;
        }
    }
}

template<int CI, bool BF16X>
__global__ __launch_bounds__(256) void aggr_kernel(
    const void* __restrict__ xv, const int2* __restrict__ se_all,
    const int* __restrict__ offs_all,
    const float* __restrict__ We_all, const float* __restrict__ be_all,
    unsigned short* __restrict__ out_hi)
{
    constexpr int KP = (CI + 31) / 32 * 32;
    int k = blockIdx.y;
    int wv = threadIdx.x >> 6, lane = threadIdx.x & 63;
    int c0 = lane * 4;
    unsigned short* o = out_hi + (size_t)k * NP * KP;
    const int2*  se   = se_all + (size_t)k * NE;
    const int*   offs = offs_all + k * (NN + 1);
    const float* We   = We_all + (size_t)k * CI;
    const float* be   = be_all + (size_t)k * CI;

    constexpr bool ACT_ALL = (64 * 4 == KP) && (CI == KP);
    bool act = ACT_ALL || (c0 < CI);
    float w[4], b[4];
    #pragma unroll
    for (int e = 0; e < 4; ++e) {
        bool a = (c0 + e) < CI;
        w[e] = a ? We[c0 + e] : 0.f;
        b[e] = a ? be[c0 + e] : 0.f;
    }

    for (int it = 0; it < 4; ++it) {
        int d = blockIdx.x * 16 + it * 4 + wv;
        if (d >= NN) {
            if (c0 < KP) { uint2 z = {0u, 0u}; *(uint2*)(o + (size_t)d * KP + c0) = z; }
            continue;
        }
        float xd[4] = {0.f, 0.f, 0.f, 0.f};
        if (act) loadrow4<CI, BF16X>(xd, xv, d, c0);
        #pragma unroll
        for (int e = 0; e < 4; ++e) if ((c0 + e) >= CI) xd[e] = 0.f;

        float den[4], num[4];
        #pragma unroll
        for (int e = 0; e < 4; ++e) {
            float mg = fmaxf(xd[e] + w[e] + b[e], 0.f);   // self loop, ea=1
            float ex = __expf(mg);
            den[e] = ex;
            num[e] = mg * ex;
        }

        auto step = [&](const float xc[4], float a) {
            #pragma unroll
            for (int e = 0; e < 4; ++e) {
                float t = xc[e] + fmaf(a, w[e], b[e]);
                float mg = fmaxf(t, 0.f);
                float ex = __expf(mg);
                den[e] += ex;
                num[e] = fmaf(mg, ex, num[e]);
            }
        };

        int start = offs[d], end = offs[d + 1];
        for (int base = start; base < end; base += 64) {
            int cnt = min(64, end - base);
            int sv = 0; float av = 0.f;
            if (lane < cnt) {
                int2 p = se[base + lane];
                sv = p.x; av = __int_as_float(p.y);
            }
            float x0[4] = {0.f,0.f,0.f,0.f}, x1[4] = {0.f,0.f,0.f,0.f};
            float x2[4] = {0.f,0.f,0.f,0.f}, x3[4] = {0.f,0.f,0.f,0.f};
            {
                int sA = __shfl(sv, 0), sB = __shfl(sv, 1);
                int sC = __shfl(sv, 2), sD = __shfl(sv, 3);
                if (act)            loadrow4<CI, BF16X>(x0, xv, sA, c0);
                if (act && cnt > 1) loadrow4<CI, BF16X>(x1, xv, sB, c0);
                if (act && cnt > 2) loadrow4<CI, BF16X>(x2, xv, sC, c0);
                if (act && cnt > 3) loadrow4<CI, BF16X>(x3, xv, sD, c0);
            }
            int j = 0;
            for (; j + 3 < cnt; j += 4) {
                float a0 = __shfl(av, j),     a1 = __shfl(av, j + 1);
                float a2 = __shfl(av, j + 2), a3 = __shfl(av, j + 3);
                int s4 = __shfl(sv, (j + 4) & 63), s5 = __shfl(sv, (j + 5) & 63);
                int s6 = __shfl(sv, (j + 6) & 63), s7 = __shfl(sv, (j + 7) & 63);
                step(x0, a0);
                if (act && (j + 4) < cnt) loadrow4<CI, BF16X>(x0, xv, s4, c0);
                step(x1, a1);
                if (act && (j + 5) < cnt) loadrow4<CI, BF16X>(x1, xv, s5, c0);
                step(x2, a2);
                if (act && (j + 6) < cnt) loadrow4<CI, BF16X>(x2, xv, s6, c0);
                step(x3, a3);
                if (act && (j + 7) < cnt) loadrow4<CI, BF16X>(x3, xv, s7, c0);
            }
            if (j < cnt)     step(x0, __shfl(av, j));
            if (j + 1 < cnt) step(x1, __shfl(av, j + 1));
            if (j + 2 < cnt) step(x2, __shfl(av, j + 2));
        }
        if (c0 < KP) {
            unsigned short r[4];
            #pragma unroll
            for (int e = 0; e < 4; ++e) {
                float v = ((c0 + e) < CI) ? (num[e] / den[e] + xd[e]) : 0.f;
                r[e] = f2bf(v);
            }
            uint2 pk = {(unsigned)r[0] | ((unsigned)r[1] << 16),
                        (unsigned)r[2] | ((unsigned)r[3] << 16)};
            *(uint2*)(o + (size_t)d * KP + c0) = pk;
        }
    }
}

// ---------------- weight split+transpose, all 6 jobs in one launch ----------------

struct SplitJob { const float* W; unsigned short* out; int kdim, ndim, np_, kp; };
struct SplitJobs { SplitJob j[6]; };

__global__ void split_all_kernel(SplitJobs jobs) {
    SplitJob jb = jobs.j[blockIdx.z];
    int idx = blockIdx.x * 256 + threadIdx.x;
    int total = KT * jb.np_ * jb.kp;
    if (idx >= total) return;
    int k = idx / (jb.np_ * jb.kp);
    int rem = idx - k * jb.np_ * jb.kp;
    int n = rem / jb.kp;
    int kk = rem - n * jb.kp;
    float v = (n < jb.ndim && kk < jb.kdim) ? jb.W[((size_t)k * jb.kdim + kk) * jb.ndim + n] : 0.f;
    jb.out[idx] = f2bf(v);
}

// ---------------- GEMM1: bf16 MFMA, dbuf K-loop, fused BN stats, LDS-coalesced C store ------
// (round-9 win: LDS C-bounce removes ~4.8x HBM write amplification)

__global__ __launch_bounds__(256, 2) void gemm1_mfma(
    const unsigned short* __restrict__ A_hi,
    const unsigned short* __restrict__ B_hi,
    const float* __restrict__ bias_all, unsigned short* __restrict__ C_all,
    float* __restrict__ psum,
    int KP, int ldc, int Mv, int Nv)
{
    __shared__ unsigned short smem[16384];   // A dbuf [0|4096], B dbuf [8192|12288]; reused as Ct[128][128]

    int z = blockIdx.z;
    int gxT = gridDim.x, gyT = gridDim.y;
    int NHP = gxT * 128;
    const unsigned short* Ahg = A_hi + (size_t)z * NP * KP;
    const unsigned short* Bhg = B_hi + (size_t)z * NHP * KP;
    const float* bias = bias_all + (size_t)z * Nv;
    unsigned short* C = C_all + (size_t)z * NP * ldc;

    int tid = threadIdx.x;
    int w = tid >> 6, l = tid & 63;
    int bm = blockIdx.y * 128, bn = blockIdx.x * 128;
    int lane15 = l & 15, quad = l >> 4;
    int wm = (w >> 1) * 64, wn = (w & 1) * 64;
    int srow = l & 15;
    int scol = (l >> 4) * 8;

    f4_t acc[4][4];
    #pragma unroll
    for (int i = 0; i < 4; ++i)
        #pragma unroll
        for (int j = 0; j < 4; ++j) { f4_t zz = {0.f,0.f,0.f,0.f}; acc[i][j] = zz; }

    size_t aoff0 = (size_t)(bm + 32 * w +  0 + srow) * KP + scol;
    size_t aoff1 = (size_t)(bm + 32 * w + 16 + srow) * KP + scol;
    size_t boff0 = (size_t)(bn + 32 * w +  0 + srow) * KP + scol;
    size_t boff1 = (size_t)(bn + 32 * w + 16 + srow) * KP + scol;
    int rb0 = 32 * w, rb1 = 32 * w + 16;
    int ta = (w >> 1) * 4, tb = (w & 1) * 4;

    // prologue: stage tile 0 into offset 0
    gload16(&smem[0 + rb0 * 32], Ahg + aoff0);
    gload16(&smem[0 + rb1 * 32], Ahg + aoff1);
    gload16(&smem[8192 + rb0 * 32], Bhg + boff0);
    gload16(&smem[8192 + rb1 * 32], Bhg + boff1);
    __syncthreads();

    int curo = 0;
    for (int k0 = 32; k0 < KP; k0 += 32) {
        int nxto = curo ^ 4096;
        gload16(&smem[nxto + rb0 * 32], Ahg + aoff0 + k0);
        gload16(&smem[nxto + rb1 * 32], Ahg + aoff1 + k0);
        gload16(&smem[8192 + nxto + rb0 * 32], Bhg + boff0 + k0);
        gload16(&smem[8192 + nxto + rb1 * 32], Bhg + boff1 + k0);

        bf8_t fa[4], fb[4];
        #pragma unroll
        for (int i = 0; i < 4; ++i) {
            fa[i] = *(const bf8_t*)&smem[curo + (ta + i) * 512 + l * 8];
            fb[i] = *(const bf8_t*)&smem[8192 + curo + (tb + i) * 512 + l * 8];
        }
        #pragma unroll
        for (int i = 0; i < 4; ++i)
            #pragma unroll
            for (int j = 0; j < 4; ++j)
                acc[i][j] = __builtin_amdgcn_mfma_f32_16x16x32_bf16(fa[i], fb[j], acc[i][j], 0, 0, 0);
        __syncthreads();
        curo = nxto;
    }
    {   // last tile
        bf8_t fa[4], fb[4];
        #pragma unroll
        for (int i = 0; i < 4; ++i) {
            fa[i] = *(const bf8_t*)&smem[curo + (ta + i) * 512 + l * 8];
            fb[i] = *(const bf8_t*)&smem[8192 + curo + (tb + i) * 512 + l * 8];
        }
        #pragma unroll
        for (int i = 0; i < 4; ++i)
            #pragma unroll
            for (int j = 0; j < 4; ++j)
                acc[i][j] = __builtin_amdgcn_mfma_f32_16x16x32_bf16(fa[i], fb[j], acc[i][j], 0, 0, 0);
    }

    __syncthreads();   // all waves done reading staging buffers; safe to reuse as C tile

    // quantize + fused BN partial stats (identical arithmetic to before); C -> LDS
    #pragma unroll
    for (int j = 0; j < 4; ++j) {
        int c = bn + wn + j * 16 + lane15;
        float bc = (c < Nv) ? bias[c] : 0.f;
        float s1 = 0.f, s2 = 0.f;
        #pragma unroll
        for (int i = 0; i < 4; ++i) {
            #pragma unroll
            for (int r5 = 0; r5 < 4; ++r5) {
                int r = bm + wm + i * 16 + quad * 4 + r5;
                float v = acc[i][j][r5] + bc;
                unsigned short q = f2bf(v);
                int lr = wm + i * 16 + quad * 4 + r5;
                int lc = wn + j * 16 + lane15;
                smem[lr * 128 + lc] = q;
                bool ok = (r < NN) && (c < Nv);
                float vq = ok ? bf2f(q) : 0.f;
                s1 += vq;
                s2 = fmaf(vq, vq, s2);
            }
        }
        s1 += __shfl_xor(s1, 16); s2 += __shfl_xor(s2, 16);
        s1 += __shfl_xor(s1, 32); s2 += __shfl_xor(s2, 32);
        if (quad == 0) {
            int wrow = w >> 1;
            int col = wn + j * 16 + lane15;
            size_t o = ((((size_t)z * gyT + blockIdx.y) * gxT + blockIdx.x) * 2 + wrow) * 256 + col * 2;
            float2 st = {s1, s2};
            *(float2*)&psum[o] = st;
        }
    }
    __syncthreads();

    // coalesced C store: 16 lanes x 16B = 256B contiguous per row segment
    int lr8 = tid >> 4;              // row 0..15 base
    int lc8 = (tid & 15) * 8;        // col 0..120
    bool cok = (bn + lc8 + 8) <= ldc;   // l=0 last tile: cols >= ldc don't exist
    if (cok) {
        #pragma unroll
        for (int p = 0; p < 8; ++p) {
            int row = p * 16 + lr8;
            uint4 v = *(const uint4*)&smem[row * 128 + lc8];
            *(uint4*)&C[(size_t)(bm + row) * ldc + bn + lc8] = v;
        }
    }
}

// ---------------- finalize BN scale/shift from partials (parallel over channel chunks) ---------

__global__ __launch_bounds__(256) void finalize_kernel(
    const float* __restrict__ psum,
    const float* __restrict__ g_all, const float* __restrict__ bt_all,
    float* __restrict__ scale_all, float* __restrict__ shift_all,
    int hid, int gxT)
{
    int z = blockIdx.x;
    int t64 = threadIdx.x & 63;
    int slice = threadIdx.x >> 6;          // 0..3 gy-slices
    int c = blockIdx.y * 64 + t64;         // channel
    __shared__ double rs1[4][64];
    __shared__ double rs2[4][64];
    double s1 = 0.0, s2 = 0.0;
    if (c < gxT * 128) {
        int gx = c >> 7, col = c & 127;
        for (int gy = slice; gy < NP / 128; gy += 4) {
            size_t base = (((size_t)z * (NP / 128) + gy) * gxT + gx) * 2 * 256 + col * 2;
            float2 a  = *(const float2*)&psum[base];
            float2 b2 = *(const float2*)&psum[base + 256];
            s1 += (double)a.x + b2.x;
            s2 += (double)a.y + b2.y;
        }
    }
    rs1[slice][t64] = s1;
    rs2[slice][t64] = s2;
    __syncthreads();
    if (slice == 0 && c < hid) {
        double S1 = rs1[0][t64] + rs1[1][t64] + rs1[2][t64] + rs1[3][t64];
        double S2 = rs2[0][t64] + rs2[1][t64] + rs2[2][t64] + rs2[3][t64];
        double mu = S1 / NN;
        double var = S2 / NN - mu * mu;
        if (var < 0.0) var = 0.0;
        float rs = (float)(1.0 / sqrt(var + 1e-5));
        float sc = rs * g_all[(size_t)z * hid + c];
        scale_all[(size_t)z * 512 + c] = sc;
        shift_all[(size_t)z * 512 + c] = bt_all[(size_t)z * hid + c] - (float)mu * sc;
    }
}

// ---------------- GEMM2: round-10 structure + counted-vmcnt pipeline (T4) -------------------
// Identical to the 68.5us round-10 kernel (64x128, BK=32, all-gload_lds, LDS params)
// EXCEPT the per-iteration sync: 3 LDS slots; each iter does
//   stage(it+1) -> s_waitcnt vmcnt(3) -> raw s_barrier -> ds_read/BN/MFMA on slot it%3.
// vmcnt(3) retires this wave's stage(it) (3 DMAs of stage(it+1) stay IN FLIGHT across
// the barrier — never drain to 0); since every wave does {own-wait, then barrier},
// after the barrier ALL waves' stage(it) has landed (RAW safe). stage(it+1) reuses the
// slot last read at iter it-2, and barrier(it-1) separates those reads from this write
// (WAR safe — the reason for 3 slots, not 2). Tail staging is clamped so the in-flight
// count stays statically 3. LDS 48KB still fits 2 blocks/CU (grid 516 caps at 2 anyway).

__global__ __launch_bounds__(256, 2) void gemm2_mfma(
    const unsigned short* __restrict__ h_all, const float* __restrict__ scale_all,
    const float* __restrict__ shift_all,
    const unsigned short* __restrict__ B_hi,
    const float* __restrict__ bb,
    float* __restrict__ outf, unsigned short* __restrict__ outb,
    int KP, int hid, int leaky, int as_bf16)
{
    __shared__ unsigned short Ah[3][64 * 32];    // 12 KB
    __shared__ unsigned short Bh[3][128 * 32];   // 24 KB
    __shared__ float sclS[KT * 512];             // 6 KB
    __shared__ float shfS[KT * 512];             // 6 KB

    int tid = threadIdx.x;
    int w = tid >> 6, l = tid & 63;
    int bm = blockIdx.y * 64, bn = blockIdx.x * 128;
    int lane15 = l & 15, quad = l >> 4;
    int wm = (w >> 1) * 32, wn = (w & 1) * 64;
    int srow = l & 15, scol = (l >> 4) * 8;

    const int KPZ = KP / 32;
    const int NIT = 3 * KPZ;

    f4_t acc[2][4];
    #pragma unroll
    for (int i = 0; i < 2; ++i)
        #pragma unroll
        for (int j = 0; j < 4; ++j) { f4_t zz = {0.f,0.f,0.f,0.f}; acc[i][j] = zz; }

    int rb0 = 32 * w, rb1 = 32 * w + 16;
    int ta = (w >> 1) * 2, tb = (w & 1) * 4;
    int grow = 16 * w + lane15;                  // A row this thread stages
    size_t arow  = (size_t)(bm + grow) * KP + quad * 8;
    size_t brow0 = (size_t)(bn + 32 * w + srow) * KP + scol;
    size_t brow1 = (size_t)(bn + 32 * w + 16 + srow) * KP + scol;

    auto stage = [&](int t, int s) {
        int zz = t / KPZ, kk = (t - zz * KPZ) * 32;
        const unsigned short* hz = h_all + (size_t)zz * NP * KP + kk;
        const unsigned short* bz = B_hi + (size_t)zz * 256 * KP + kk;
        gload16(&Ah[s][tid * 8], hz + arow);
        gload16(&Bh[s][rb0 * 32], bz + brow0);
        gload16(&Bh[s][rb1 * 32], bz + brow1);
    };

    // prologue: scale/shift -> LDS; stage tile 0; one-time full drain
    for (int idx = tid; idx < KT * 512; idx += 256) {
        sclS[idx] = scale_all[idx];
        shfS[idx] = shift_all[idx];
    }
    stage(0, 0);
    __syncthreads();

    for (int it = 0; it < NIT; ++it) {
        // issue next-tile DMAs (clamped tail keeps in-flight count static)
        stage(min(it + 1, NIT - 1), (it + 1) % 3);
        // retire own stage(it); stage(it+1) stays in flight across the barrier
        asm volatile("s_waitcnt vmcnt(3)" ::: "memory");
        __builtin_amdgcn_s_barrier();            // all waves' stage(it) now landed
        __builtin_amdgcn_sched_barrier(0);       // pin following ds_reads after barrier

        int cs = it % 3;
        int zz = it / KPZ, kk = (it - zz * KPZ) * 32;
        int chb = kk + quad * 8;
        float4 s0 = *(const float4*)&sclS[zz * 512 + chb];
        float4 s1 = *(const float4*)&sclS[zz * 512 + chb + 4];
        float4 t0 = *(const float4*)&shfS[zz * 512 + chb];
        float4 t1 = *(const float4*)&shfS[zz * 512 + chb + 4];
        float ss[8] = {s0.x, s0.y, s0.z, s0.w, s1.x, s1.y, s1.z, s1.w};
        float tt[8] = {t0.x, t0.y, t0.z, t0.w, t1.x, t1.y, t1.z, t1.w};
        bf8_t fr0 = *(const bf8_t*)&Ah[cs][(ta + 0) * 512 + l * 8];
        bf8_t fr1 = *(const bf8_t*)&Ah[cs][(ta + 1) * 512 + l * 8];
        bf8_t fb[4];
        #pragma unroll
        for (int j = 0; j < 4; ++j)
            fb[j] = *(const bf8_t*)&Bh[cs][(tb + j) * 512 + l * 8];
        bf8_t fa0, fa1;
        #pragma unroll
        for (int e = 0; e < 8; ++e) {
            bool okc = (chb + e) < hid;
            float x0 = bf2f((unsigned short)fr0[e]);
            float x1 = bf2f((unsigned short)fr1[e]);
            float v0 = okc ? fmaxf(fmaf(x0, ss[e], tt[e]), 0.f) : 0.f;
            float v1 = okc ? fmaxf(fmaf(x1, ss[e], tt[e]), 0.f) : 0.f;
            fa0[e] = (short)f2bf(v0);
            fa1[e] = (short)f2bf(v1);
        }
        #pragma unroll
        for (int j = 0; j < 4; ++j) {
            acc[0][j] = __builtin_amdgcn_mfma_f32_16x16x32_bf16(fa0, fb[j], acc[0][j], 0, 0, 0);
            acc[1][j] = __builtin_amdgcn_mfma_f32_16x16x32_bf16(fa1, fb[j], acc[1][j], 0, 0, 0);
        }
    }

    // epilogue: + sum-of-biases, leaky, store final (acc already sums the 3 link types)
    #pragma unroll
    for (int j = 0; j < 4; ++j) {
        int c = bn + wn + j * 16 + lane15;
        float bsum = bb[c] + bb[256 + c] + bb[512 + c];
        #pragma unroll
        for (int i = 0; i < 2; ++i) {
            #pragma unroll
            for (int r5 = 0; r5 < 4; ++r5) {
                int r = bm + wm + i * 16 + quad * 4 + r5;
                if (r < NN) {
                    float v = acc[i][j][r5] + bsum;
                    if (leaky) v = (v > 0.f) ? v : 0.01f * v;
                    if (as_bf16) outb[(size_t)r * 256 + c] = f2bf(v);
                    else         outf[(size_t)r * 256 + c] = v;
                }
            }
        }
    }
}

// ---------------- host ----------------

extern "C" void kernel_launch(void* const* d_in, const int* in_sizes, int n_in,
                              void* d_out, int out_size, void* d_ws, size_t ws_size,
                              hipStream_t stream)
{
    const float* x  = (const float*)d_in[0];
    const int*   ei = (const int*)d_in[1];
    const float* ea = (const float*)d_in[2];

    char* w = (char*)d_ws;
    auto alloc = [&](size_t bytes) {
        char* p = w;
        w += (bytes + 255) & ~(size_t)255;
        return p;
    };
    int* deg    = (int*)alloc((size_t)KT * NN * 4);
    int* offs   = (int*)alloc((size_t)KT * (NN + 1) * 4);
    int* cursor = (int*)alloc((size_t)KT * NN * 4);
    int2* se    = (int2*)alloc((size_t)KT * NE * 8);
    unsigned short* a1_hi = (unsigned short*)alloc((size_t)KT * NP * 256 * 2);
    unsigned short* h3 = (unsigned short*)alloc((size_t)KT * NP * 512 * 2);
    unsigned short* bta_l[3];
    unsigned short* btb_l[3];
    for (int l = 0; l < 3; ++l) {
        bta_l[l] = (unsigned short*)alloc((size_t)KT * 512 * 256 * 2);
        btb_l[l] = (unsigned short*)alloc((size_t)KT * 256 * 512 * 2);
    }
    float* psum = (float*)alloc((size_t)KT * (NP / 128) * 4 * 2 * 256 * 4);
    float* scale3 = (float*)alloc((size_t)KT * 512 * 4);
    float* shift3 = (float*)alloc((size_t)KT * 512 * 4);
    unsigned short* bufA = (unsigned short*)alloc((size_t)NN * 256 * 2);
    unsigned short* bufB = (unsigned short*)alloc((size_t)NN * 256 * 2);

    (void)hipMemsetAsync(deg, 0, (size_t)KT * NN * 4, stream);
    int net = KT * NE;
    deg_kernel<<<(net + 255) / 256, 256, 0, stream>>>(ei, deg);
    scan_kernel<<<KT, 256, 0, stream>>>(deg, offs, cursor);
    scatter_kernel<<<(net + 255) / 256, 256, 0, stream>>>(ei, ea, cursor, se);

    SplitJobs jobs;
    int maxtot = 0;
    for (int l = 0; l < 3; ++l) {
        int ci  = (l == 0) ? 170 : 256;
        int KP1 = (ci + 31) / 32 * 32;
        int hid = 2 * ci;
        int NHP = (hid + 127) / 128 * 128;
        int KP2 = (hid + 31) / 32 * 32;
        jobs.j[2 * l]     = { (const float*)d_in[3 + 8 * l + 2], bta_l[l], ci,  hid, NHP, KP1 };
        jobs.j[2 * l + 1] = { (const float*)d_in[3 + 8 * l + 6], btb_l[l], hid, 256, 256, KP2 };
        maxtot = max(maxtot, KT * NHP * KP1);
        maxtot = max(maxtot, KT * 256 * KP2);
    }
    dim3 gsp((maxtot + 255) / 256, 1, 6);
    split_all_kernel<<<gsp, 256, 0, stream>>>(jobs);

    const void* hin = x;
    for (int l = 0; l < 3; ++l) {
        int ci  = (l == 0) ? 170 : 256;
        int KP1 = (ci + 31) / 32 * 32;        // 192 / 256
        int hid = 2 * ci;                     // 340 / 512
        int NHP = (hid + 127) / 128 * 128;    // 384 / 512
        int KP2 = (hid + 31) / 32 * 32;       // 352 / 512
        const float* We = (const float*)d_in[3 + 8 * l + 0];
        const float* be = (const float*)d_in[3 + 8 * l + 1];
        const float* ba = (const float*)d_in[3 + 8 * l + 3];
        const float* g  = (const float*)d_in[3 + 8 * l + 4];
        const float* bt = (const float*)d_in[3 + 8 * l + 5];
        const float* bb = (const float*)d_in[3 + 8 * l + 7];

        dim3 ga(NP / 16, KT);
        if (l == 0)
            aggr_kernel<170, false><<<ga, 256, 0, stream>>>(hin, se, offs, We, be, a1_hi);
        else
            aggr_kernel<256, true><<<ga, 256, 0, stream>>>(hin, se, offs, We, be, a1_hi);

        dim3 g1(NHP / 128, NP / 128, KT);
        gemm1_mfma<<<g1, 256, 0, stream>>>(a1_hi, bta_l[l], ba, h3, psum, KP1, KP2, NN, hid);

        dim3 gf(KT, 8);
        finalize_kernel<<<gf, 256, 0, stream>>>(psum, g, bt, scale3, shift3, hid, NHP / 128);

        unsigned short* outb = (l == 0) ? bufA : bufB;
        dim3 g2(2, NP / 64);
        gemm2_mfma<<<g2, 256, 0, stream>>>(h3, scale3, shift3, btb_l[l], bb,
                                           (float*)d_out, outb, KP2, hid,
                                           (l < 2) ? 1 : 0, (l < 2) ? 1 : 0);

        hin = (l < 2) ? (const void*)outb : nullptr;
    }
}